// Round 6
// baseline (352.132 us; speedup 1.0000x reference)
//
#include <hip/hip_runtime.h>

typedef unsigned int u32;
typedef unsigned short u16;
typedef __attribute__((ext_vector_type(8))) short short8;
typedef __attribute__((ext_vector_type(4))) float floatx4;

#define NB 4
#define NF 5
#define NN 2048
#define NDM 256
#define NBF (NB*NF)          // 20
#define NBFN (NBF*NN)        // 40960
#define NBFD (NBF*NDM)       // 5120

#define AS1 __attribute__((address_space(1)))
#define AS3 __attribute__((address_space(3)))

// Static device scratch; everything read is fully rewritten each call.
__device__ u16    g_xb[(size_t)NBF*NN*NDM];   // bf16 copy of x
__device__ u16    g_yb[(size_t)NBF*NN*NDM];   // bf16 copy of y
__device__ float  g_a2[NBFN];                 // row sumsq of x
__device__ float  g_b2[NBFN];                 // row sumsq of y
__device__ float  g_rpart[(size_t)4*NBFN];    // partial row mins: plane = jq
__device__ float  g_cpart[(size_t)64*NBFN];   // partial col mins: plane = i0t*4+w
__device__ float  g_pmn[2][(size_t)32*NBFD];  // per-chunk partial min over n
__device__ float  g_pmx[2][(size_t)32*NBFD];  // per-chunk partial max over n
__device__ float  g_bfsum[2*NBF];             // per-(dir,bf) sum of mins (atomicAdd)
__device__ float4 g_coef[NBFD];               // sx, ox, sy, oy per (bf,d)

__device__ __forceinline__ u16 cvt_bf16(float f){    // RNE
  u32 b = __float_as_uint(f);
  return (u16)((b + 0x7FFFu + ((b >> 16) & 1u)) >> 16);
}
__device__ __forceinline__ float bf2f(short v){
  return __uint_as_float(((u32)(u16)v) << 16);
}

// K1: single pass over x,y: bf16 convert + per-(bf,d) partial min/max +
// row sumsq via LDS matrix reduction (NO serialized shfl chains in the
// main loop — every iteration is independent). Block = 64 rows.
__global__ void __launch_bounds__(256) k_prep(const float* __restrict__ x,
                                              const float* __restrict__ y){
  __shared__ float sS[64][65];                // per-(row,lane) sumsq partials
  __shared__ float sp[4][64];                 // stage-2 partials
  __shared__ float4 smn[4][64], smx[4][64];
  int bi = blockIdx.x;                        // 2 * 20 * 32 = 1280
  if (bi == 0 && threadIdx.x < 2*NBF) g_bfsum[threadIdx.x] = 0.f;
  int tensor = bi >= (NBF*32); int rem = bi - tensor*(NBF*32);
  int bf = rem >> 5; int chunk = rem & 31;
  size_t rbase = (size_t)bf*NN + (size_t)chunk*64;
  const float* src = (tensor ? y : x) + rbase*NDM;
  u16*  dst  = (tensor ? g_yb : g_xb) + rbase*NDM;
  float* sums = (tensor ? g_b2 : g_a2) + bf*NN + chunk*64;
  int w = threadIdx.x >> 6, l = threadIdx.x & 63;

  float4 vmn = make_float4(INFINITY,INFINITY,INFINITY,INFINITY);
  float4 vmx = make_float4(-INFINITY,-INFINITY,-INFINITY,-INFINITY);
  for (int i = 0; i < 16; ++i){
    int row = w + 4*i;
    float4 v = ((const float4*)(src + (size_t)row*NDM))[l];
    sS[row][l] = v.x*v.x + v.y*v.y + v.z*v.z + v.w*v.w;
    ((ushort4*)(dst + (size_t)row*NDM))[l] =
        make_ushort4(cvt_bf16(v.x), cvt_bf16(v.y), cvt_bf16(v.z), cvt_bf16(v.w));
    vmn.x = fminf(vmn.x, v.x); vmn.y = fminf(vmn.y, v.y);
    vmn.z = fminf(vmn.z, v.z); vmn.w = fminf(vmn.w, v.w);
    vmx.x = fmaxf(vmx.x, v.x); vmx.y = fmaxf(vmx.y, v.y);
    vmx.z = fmaxf(vmx.z, v.z); vmx.w = fmaxf(vmx.w, v.w);
  }
  smn[w][l] = vmn; smx[w][l] = vmx;
  __syncthreads();
  // row-sumsq reduce, stage 1: 4 threads per row sum 16 lanes each.
  {
    int row = threadIdx.x & 63, q = threadIdx.x >> 6;
    float p = 0.f;
    #pragma unroll
    for (int i = 0; i < 16; ++i) p += sS[row][q*16 + i];
    sp[q][row] = p;
  }
  __syncthreads();
  if (threadIdx.x < 64)
    sums[threadIdx.x] = sp[0][threadIdx.x] + sp[1][threadIdx.x]
                      + sp[2][threadIdx.x] + sp[3][threadIdx.x];
  if (w == 0){
    float4 a = smn[0][l], b_ = smn[1][l], c = smn[2][l], d = smn[3][l];
    float4 e = smx[0][l], f = smx[1][l], g = smx[2][l], h = smx[3][l];
    float4 mn4 = make_float4(fminf(fminf(a.x,b_.x), fminf(c.x,d.x)),
                             fminf(fminf(a.y,b_.y), fminf(c.y,d.y)),
                             fminf(fminf(a.z,b_.z), fminf(c.z,d.z)),
                             fminf(fminf(a.w,b_.w), fminf(c.w,d.w)));
    float4 mx4 = make_float4(fmaxf(fmaxf(e.x,f.x), fmaxf(g.x,h.x)),
                             fmaxf(fmaxf(e.y,f.y), fmaxf(g.y,h.y)),
                             fmaxf(fmaxf(e.z,f.z), fmaxf(g.z,h.z)),
                             fmaxf(fmaxf(e.w,f.w), fmaxf(g.w,h.w)));
    ((float4*)&g_pmn[tensor][(size_t)chunk*NBFD + bf*NDM])[l] = mn4;
    ((float4*)&g_pmx[tensor][(size_t)chunk*NBFD + bf*NDM])[l] = mx4;
  }
}

// K2: GEMM. R5 lesson: with the XCD swizzle FETCH hit 25MB but dur didn't
// move — we're AT the 2-barrier structure's ~600-700TF ceiling (m233: the
// stage+vmcnt(0)+barrier path is ~72% of each phase). R6: the B-panel
// (256KB per (bf,jq), shared by 16 consecutive works on one XCD) is
// L2-RESIDENT after the swizzle, so drop LDS staging entirely: read B
// fragments global->VGPR (L2 hit), ZERO barriers, zero LDS. L2 traffic
// 1280 x 1MB = 1.31GB @ 34.5TB/s -> 38us floor vs 64.5 now. Explicit
// compile-time ping-pong (b0/b1, fully unrolled => static reg indexing).
// (256,1) so the allocator has full budget (af 64 + acc 64 + b0/b1 64 +
// misc ~= 235 VGPR) and cannot clamp-spill (R1/R4 failure mode).
__global__ void __launch_bounds__(256, 1) k_gemm(){
  const int orig = blockIdx.x;                // 0..1279
  const int work = (orig & 7)*160 + (orig >> 3);  // XCD gets contiguous 160
  const int bf  = work >> 6;                  // panel-major: (bf,jq) outer
  const int jq  = (work >> 4) & 3;            // cols jq*512 .. +511
  const int i0t = work & 15;
  const int i0  = i0t * 128;
  const int t = threadIdx.x;
  const int w = t >> 6, l = t & 63;
  const int quad = l >> 4, c16 = l & 15;
  const int wrow = w * 32;                    // wave's 32-row slice
  const u16* xb = g_xb + (size_t)bf * NN * NDM;
  const u16* yb = g_yb + (size_t)bf * NN * NDM;
  const float* b2 = g_b2 + bf*NN + jq*512;

  short8 af[2][8];
  #pragma unroll
  for (int mb = 0; mb < 2; ++mb){
    const u16* rp = xb + (size_t)(i0 + wrow + mb*16 + c16) * NDM + quad*8;
    #pragma unroll
    for (int ks = 0; ks < 8; ++ks)
      af[mb][ks] = *(const short8*)(rp + ks*32);
  }
  const float* a2 = g_a2 + bf*NN + i0 + wrow;
  float a2r[2][4];
  #pragma unroll
  for (int mb = 0; mb < 2; ++mb)
    #pragma unroll
    for (int r = 0; r < 4; ++r)
      a2r[mb][r] = a2[mb*16 + quad*4 + r];

  float rm[2][4];
  #pragma unroll
  for (int mb = 0; mb < 2; ++mb)
    #pragma unroll
    for (int r = 0; r < 4; ++r) rm[mb][r] = INFINITY;

  for (int jj = 0; jj < 4; ++jj){
    const int j0 = jq*512 + jj*128;
    // per-lane B-fragment base: col j0+nb*16+c16, k = ksl*32 + quad*8.
    const u16* bp = yb + (size_t)(j0 + c16)*NDM + quad*8;
    floatx4 acc[2][8] = {};
    short8 b0[8], b1[8];
    #pragma unroll
    for (int nb = 0; nb < 8; ++nb)
      b0[nb] = *(const short8*)(bp + nb*16*NDM);
    #pragma unroll
    for (int ksl = 0; ksl < 8; ++ksl){
      if (ksl < 7){                           // prefetch next k-slice
        const u16* np = bp + (ksl+1)*32;
        if ((ksl & 1) == 0){
          #pragma unroll
          for (int nb = 0; nb < 8; ++nb)
            b1[nb] = *(const short8*)(np + nb*16*NDM);
        } else {
          #pragma unroll
          for (int nb = 0; nb < 8; ++nb)
            b0[nb] = *(const short8*)(np + nb*16*NDM);
        }
      }
      #pragma unroll
      for (int mb = 0; mb < 2; ++mb)
        #pragma unroll
        for (int nb = 0; nb < 8; ++nb)
          acc[mb][nb] = __builtin_amdgcn_mfma_f32_16x16x32_bf16(
              af[mb][ksl], (ksl & 1) ? b1[nb] : b0[nb], acc[mb][nb], 0, 0, 0);
    }
    float bcol[8], colm[8];
    #pragma unroll
    for (int nb = 0; nb < 8; ++nb){
      bcol[nb] = b2[jj*128 + nb*16 + c16];    // L1/L2-hot, shared by 16 blocks
      colm[nb] = INFINITY;
    }
    #pragma unroll
    for (int mb = 0; mb < 2; ++mb)
      #pragma unroll
      for (int r = 0; r < 4; ++r)
        #pragma unroll
        for (int nb = 0; nb < 8; ++nb){
          float dd = a2r[mb][r] + bcol[nb] - 2.0f * acc[mb][nb][r];
          rm[mb][r] = fminf(rm[mb][r], dd);
          colm[nb] = fminf(colm[nb], dd);
        }
    #pragma unroll
    for (int nb = 0; nb < 8; ++nb){
      float cm = colm[nb];
      cm = fminf(cm, __shfl_xor(cm, 16, 64));
      cm = fminf(cm, __shfl_xor(cm, 32, 64));
      if (quad == 0)
        g_cpart[(size_t)(i0t*4 + w)*NBFN + bf*NN + j0 + nb*16 + c16] = cm;
    }
  }
  #pragma unroll
  for (int mb = 0; mb < 2; ++mb)
    #pragma unroll
    for (int r = 0; r < 4; ++r){
      float v = rm[mb][r];
      v = fminf(v, __shfl_xor(v, 1, 64));
      v = fminf(v, __shfl_xor(v, 2, 64));
      v = fminf(v, __shfl_xor(v, 4, 64));
      v = fminf(v, __shfl_xor(v, 8, 64));
      if (c16 == 0)
        g_rpart[(size_t)jq*NBFN + bf*NN + i0 + wrow + mb*16 + quad*4 + r] = v;
    }
}

// K3: hierarchical reduce of partial-min planes -> per-bf sums (atomicAdd).
__global__ void __launch_bounds__(256) k_weight(){
  int bf = blockIdx.x >> 3;
  int chunk = blockIdx.x & 7;
  int i = chunk*256 + threadIdx.x;            // row index in [0,2048)
  size_t base = (size_t)bf*NN + i;
  float m = INFINITY, c = INFINITY;
  #pragma unroll
  for (int p = 0; p < 4; ++p)  m = fminf(m, g_rpart[(size_t)p*NBFN + base]);
  #pragma unroll
  for (int p = 0; p < 64; ++p) c = fminf(c, g_cpart[(size_t)p*NBFN + base]);
  float srow = m, scol = c;
  #pragma unroll
  for (int mm = 1; mm < 64; mm <<= 1){
    srow += __shfl_xor(srow, mm, 64);
    scol += __shfl_xor(scol, mm, 64);
  }
  __shared__ float pr[4], pcn[4];
  int w = threadIdx.x >> 6, l = threadIdx.x & 63;
  if (l == 0){ pr[w] = srow; pcn[w] = scol; }
  __syncthreads();
  if (threadIdx.x == 0){
    atomicAdd(&g_bfsum[bf],       pr[0]+pr[1]+pr[2]+pr[3]);
    atomicAdd(&g_bfsum[NBF + bf], pcn[0]+pcn[1]+pcn[2]+pcn[3]);
  }
}

// K4: fold weights + min/max partials into per-(bf,d) affine coefficients.
__global__ void k_coef(){
  int idx = blockIdx.x * 256 + threadIdx.x;   // < NBFD
  int bf = idx >> 8;
  int b = bf / NF;
  float swx = 0.f, swy = 0.f;
  #pragma unroll
  for (int f = 0; f < NF; ++f){
    swx += g_bfsum[b*NF + f];
    swy += g_bfsum[NBF + b*NF + f];
  }
  float wx = 1.0f / (1.0f + swx * (1.0f/(NF*NN)));
  float wy = 1.0f / (1.0f + swy * (1.0f/(NF*NN)));
  float mnx = INFINITY, mxx = -INFINITY, mny = INFINITY, mxy = -INFINITY;
  #pragma unroll
  for (int c = 0; c < 32; ++c){
    mnx = fminf(mnx, g_pmn[0][(size_t)c*NBFD + idx]);
    mxx = fmaxf(mxx, g_pmx[0][(size_t)c*NBFD + idx]);
    mny = fminf(mny, g_pmn[1][(size_t)c*NBFD + idx]);
    mxy = fmaxf(mxy, g_pmx[1][(size_t)c*NBFD + idx]);
  }
  float sx = wx / (mxx - mnx), sy = wy / (mxy - mny);
  g_coef[idx] = make_float4(sx, -sx * mnx, sy, -sy * mny);
}

// K5: out = sx*xb + ox + sy*yb + oy from the L3-hot bf16 copies (halves
// read bytes vs fp32 x,y). One thread per 8 elements; flat 5120-block grid.
__global__ void __launch_bounds__(256) k_out(floatx4* __restrict__ out){
  size_t e0 = ((size_t)blockIdx.x * 256 + threadIdx.x) * 8;  // elem index
  int bf = (int)(e0 >> 19);                   // NN*NDM = 2^19
  int d0 = (int)(e0 & 255);
  short8 xv = *(const short8*)&g_xb[e0];
  short8 yv = *(const short8*)&g_yb[e0];
  const float4* cf = &g_coef[bf*256 + d0];
  floatx4 o0, o1;
  #pragma unroll
  for (int j = 0; j < 4; ++j){
    float4 c = cf[j];
    o0[j] = c.x * bf2f(xv[j]) + c.y + c.z * bf2f(yv[j]) + c.w;
  }
  #pragma unroll
  for (int j = 0; j < 4; ++j){
    float4 c = cf[4 + j];
    o1[j] = c.x * bf2f(xv[4 + j]) + c.y + c.z * bf2f(yv[4 + j]) + c.w;
  }
  __builtin_nontemporal_store(o0, &out[e0 >> 2]);
  __builtin_nontemporal_store(o1, &out[(e0 >> 2) + 1]);
}

extern "C" void kernel_launch(void* const* d_in, const int* in_sizes, int n_in,
                              void* d_out, int out_size, void* d_ws, size_t ws_size,
                              hipStream_t stream) {
  const float* x = (const float*)d_in[0];
  const float* y = (const float*)d_in[1];
  (void)d_ws; (void)ws_size; (void)in_sizes; (void)n_in; (void)out_size;

  k_prep  <<<dim3(1280), dim3(256), 0, stream>>>(x, y);
  k_gemm  <<<dim3(1280), dim3(256), 0, stream>>>();
  k_weight<<<dim3(160),  dim3(256), 0, stream>>>();
  k_coef  <<<dim3(20),   dim3(256), 0, stream>>>();
  k_out   <<<dim3(5120), dim3(256), 0, stream>>>((floatx4*)d_out);
}

// Round 7
// 233.826 us; speedup vs baseline: 1.5060x; 1.5060x over previous
//
#include <hip/hip_runtime.h>

typedef unsigned int u32;
typedef unsigned short u16;
typedef __attribute__((ext_vector_type(8))) short short8;
typedef __attribute__((ext_vector_type(4))) float floatx4;

#define NB 4
#define NF 5
#define NN 2048
#define NDM 256
#define NBF (NB*NF)          // 20
#define NBFN (NBF*NN)        // 40960
#define NBFD (NBF*NDM)       // 5120

#define AS1 __attribute__((address_space(1)))
#define AS3 __attribute__((address_space(3)))

// Static device scratch. Key arrays (g_rk/g_ck/g_mnk/g_mxk) use the
// order-monotone uint encoding with atomicMax and identity 0: zero-init
// (.bss) makes call 1 correct; k_fin resets them for subsequent calls;
// atomicMax is idempotent under rocprof kernel-replay.
__device__ u16    g_xb[(size_t)NBF*NN*NDM];   // bf16 copy of x
__device__ u16    g_yb[(size_t)NBF*NN*NDM];   // bf16 copy of y
__device__ float  g_a2[NBFN];                 // row sumsq of x
__device__ float  g_b2[NBFN];                 // row sumsq of y
__device__ u32    g_rk[NBFN];                 // max over ~key(row-min d(x_i, y))
__device__ u32    g_ck[NBFN];                 // max over ~key(col-min d(y_j, x))
__device__ u32    g_mnk[2][NBFD];             // max over ~key(v)  -> per-(bf,d) min
__device__ u32    g_mxk[2][NBFD];             // max over  key(v)  -> per-(bf,d) max
__device__ float4 g_coef[NBFD];               // sx, ox, sy, oy per (bf,d)

__device__ __forceinline__ u16 cvt_bf16(float f){    // RNE
  u32 b = __float_as_uint(f);
  return (u16)((b + 0x7FFFu + ((b >> 16) & 1u)) >> 16);
}
__device__ __forceinline__ float bf2f(short v){
  return __uint_as_float(((u32)(u16)v) << 16);
}
__device__ __forceinline__ void load16(const void* g, void* l){
  __builtin_amdgcn_global_load_lds((AS1 const void*)g, (AS3 void*)l, 16, 0, 0);
}
// order-monotone float<->uint: f1<f2 <=> fkey(f1)<fkey(f2) (no NaNs here)
__device__ __forceinline__ u32 fkey(float f){
  u32 b = __float_as_uint(f);
  return (b & 0x80000000u) ? ~b : (b | 0x80000000u);
}
__device__ __forceinline__ float fdec(u32 k){
  return __uint_as_float((k & 0x80000000u) ? (k ^ 0x80000000u) : ~k);
}

// K1: single pass over x,y: bf16 convert + per-(bf,d) min/max (atomicMax
// keyed) + row sumsq via LDS matrix reduction. Block = 64 rows.
__global__ void __launch_bounds__(256) k_prep(const float* __restrict__ x,
                                              const float* __restrict__ y){
  __shared__ float sS[64][65];                // per-(row,lane) sumsq partials
  __shared__ float sp[4][64];                 // stage-2 partials
  __shared__ float4 smn[4][64], smx[4][64];
  int bi = blockIdx.x;                        // 2 * 20 * 32 = 1280
  int tensor = bi >= (NBF*32); int rem = bi - tensor*(NBF*32);
  int bf = rem >> 5; int chunk = rem & 31;
  size_t rbase = (size_t)bf*NN + (size_t)chunk*64;
  const float* src = (tensor ? y : x) + rbase*NDM;
  u16*  dst  = (tensor ? g_yb : g_xb) + rbase*NDM;
  float* sums = (tensor ? g_b2 : g_a2) + bf*NN + chunk*64;
  int w = threadIdx.x >> 6, l = threadIdx.x & 63;

  float4 vmn = make_float4(INFINITY,INFINITY,INFINITY,INFINITY);
  float4 vmx = make_float4(-INFINITY,-INFINITY,-INFINITY,-INFINITY);
  for (int i = 0; i < 16; ++i){
    int row = w + 4*i;
    float4 v = ((const float4*)(src + (size_t)row*NDM))[l];
    sS[row][l] = v.x*v.x + v.y*v.y + v.z*v.z + v.w*v.w;
    ((ushort4*)(dst + (size_t)row*NDM))[l] =
        make_ushort4(cvt_bf16(v.x), cvt_bf16(v.y), cvt_bf16(v.z), cvt_bf16(v.w));
    vmn.x = fminf(vmn.x, v.x); vmn.y = fminf(vmn.y, v.y);
    vmn.z = fminf(vmn.z, v.z); vmn.w = fminf(vmn.w, v.w);
    vmx.x = fmaxf(vmx.x, v.x); vmx.y = fmaxf(vmx.y, v.y);
    vmx.z = fmaxf(vmx.z, v.z); vmx.w = fmaxf(vmx.w, v.w);
  }
  smn[w][l] = vmn; smx[w][l] = vmx;
  __syncthreads();
  // row-sumsq reduce, stage 1: 4 threads per row sum 16 lanes each.
  {
    int row = threadIdx.x & 63, q = threadIdx.x >> 6;
    float p = 0.f;
    #pragma unroll
    for (int i = 0; i < 16; ++i) p += sS[row][q*16 + i];
    sp[q][row] = p;
  }
  __syncthreads();
  if (threadIdx.x < 64)
    sums[threadIdx.x] = sp[0][threadIdx.x] + sp[1][threadIdx.x]
                      + sp[2][threadIdx.x] + sp[3][threadIdx.x];
  if (w == 0){
    float4 a = smn[0][l], b_ = smn[1][l], c = smn[2][l], d = smn[3][l];
    float4 e = smx[0][l], f = smx[1][l], g = smx[2][l], h = smx[3][l];
    float4 mn4 = make_float4(fminf(fminf(a.x,b_.x), fminf(c.x,d.x)),
                             fminf(fminf(a.y,b_.y), fminf(c.y,d.y)),
                             fminf(fminf(a.z,b_.z), fminf(c.z,d.z)),
                             fminf(fminf(a.w,b_.w), fminf(c.w,d.w)));
    float4 mx4 = make_float4(fmaxf(fmaxf(e.x,f.x), fmaxf(g.x,h.x)),
                             fmaxf(fmaxf(e.y,f.y), fmaxf(g.y,h.y)),
                             fmaxf(fmaxf(e.z,f.z), fmaxf(g.z,h.z)),
                             fmaxf(fmaxf(e.w,f.w), fmaxf(g.w,h.w)));
    u32 base = (u32)bf*NDM + 4*l;
    atomicMax(&g_mnk[tensor][base+0], ~fkey(mn4.x));
    atomicMax(&g_mnk[tensor][base+1], ~fkey(mn4.y));
    atomicMax(&g_mnk[tensor][base+2], ~fkey(mn4.z));
    atomicMax(&g_mnk[tensor][base+3], ~fkey(mn4.w));
    atomicMax(&g_mxk[tensor][base+0],  fkey(mx4.x));
    atomicMax(&g_mxk[tensor][base+1],  fkey(mx4.y));
    atomicMax(&g_mxk[tensor][base+2],  fkey(mx4.z));
    atomicMax(&g_mxk[tensor][base+3],  fkey(mx4.w));
  }
}

// K2: GEMM. R6 lesson: global->VGPR B (no LDS) is latency-bound (8% MFMA,
// 205us) — depth-1 reg prefetch can't hide L2 latency. Reverted to the
// proven R5 body (BK=128 dbuf + XCD panel swizzle, 64.4us). Delta vs R5:
// epilogue writes row/col mins via keyed atomicMax (g_rk/g_ck) instead of
// 11MB of rpart/cpart planes — kills the plane round-trip and k_weight's
// 64-plane latency-bound gather.
__global__ void __launch_bounds__(256, 2) k_gemm(){
  __shared__ u16 Bs[2][128*128];              // 2 x 32 KB: [buf][row*128 + k]
  __shared__ float b2s[512];                  // b2 for the j-quarter
  const int orig = blockIdx.x;                // 0..1279
  const int work = (orig & 7)*160 + (orig >> 3);  // XCD gets contiguous 160
  const int bf  = work >> 6;                  // panel-major: (bf,jq) outer
  const int jq  = (work >> 4) & 3;            // cols jq*512 .. +511
  const int i0t = work & 15;
  const int i0  = i0t * 128;
  const int t = threadIdx.x;
  const int w = t >> 6, l = t & 63;
  const int quad = l >> 4, c16 = l & 15;
  const int wrow = w * 32;                    // wave's 32-row slice
  const u16* xb = g_xb + (size_t)bf * NN * NDM;
  const u16* yb = g_yb + (size_t)bf * NN * NDM;

  const float* b2 = g_b2 + bf*NN;
  ((float2*)b2s)[t] = ((const float2*)(b2 + jq*512))[t];

  short8 af[2][8];
  #pragma unroll
  for (int mb = 0; mb < 2; ++mb){
    const u16* rp = xb + (size_t)(i0 + wrow + mb*16 + c16) * NDM + quad*8;
    #pragma unroll
    for (int ks = 0; ks < 8; ++ks)
      af[mb][ks] = *(const short8*)(rp + ks*32);
  }
  const float* a2 = g_a2 + bf*NN + i0 + wrow;
  float a2r[2][4];
  #pragma unroll
  for (int mb = 0; mb < 2; ++mb)
    #pragma unroll
    for (int r = 0; r < 4; ++r)
      a2r[mb][r] = a2[mb*16 + quad*4 + r];

  float rm[2][4];
  #pragma unroll
  for (int mb = 0; mb < 2; ++mb)
    #pragma unroll
    for (int r = 0; r < 4; ++r) rm[mb][r] = INFINITY;

  auto stage = [&](int jt, int h, int bb){
    const int j0 = jq*512 + jt*128;
    #pragma unroll
    for (int q = 0; q < 8; ++q){
      const int row = q*16 + w*4 + (l >> 4);  // 0..127
      const int c = (l & 15) ^ (row & 15);
      load16(yb + (size_t)(j0 + row)*NDM + h*128 + c*8,
             &Bs[bb][(q*16 + w*4)*128]);
    }
  };

  int buf = 0;
  stage(0, 0, 0);
  for (int jj = 0; jj < 4; ++jj){
    const int j0 = jq*512 + jj*128;
    floatx4 acc[2][8] = {};
    #pragma unroll
    for (int h = 0; h < 2; ++h){
      __syncthreads();                        // drains aged prefetch
      const int nit = jj*2 + h + 1;
      if (nit < 8) stage(nit >> 1, nit & 1, buf ^ 1);
      #pragma unroll
      for (int ksl = 0; ksl < 4; ++ksl){
        const int lc = ((ksl*4 + quad) ^ c16) * 8;   // de-swizzle
        short8 bq[8];
        #pragma unroll
        for (int nb = 0; nb < 8; ++nb)
          bq[nb] = *(const short8*)&Bs[buf][(nb*16 + c16)*128 + lc];
        #pragma unroll
        for (int mb = 0; mb < 2; ++mb)
          #pragma unroll
          for (int nb = 0; nb < 8; ++nb)
            acc[mb][nb] = __builtin_amdgcn_mfma_f32_16x16x32_bf16(af[mb][h*4+ksl], bq[nb], acc[mb][nb], 0, 0, 0);
      }
      buf ^= 1;
    }
    float bcol[8], colm[8];
    #pragma unroll
    for (int nb = 0; nb < 8; ++nb){
      bcol[nb] = b2s[jj*128 + nb*16 + c16];
      colm[nb] = INFINITY;
    }
    #pragma unroll
    for (int mb = 0; mb < 2; ++mb)
      #pragma unroll
      for (int r = 0; r < 4; ++r)
        #pragma unroll
        for (int nb = 0; nb < 8; ++nb){
          float dd = a2r[mb][r] + bcol[nb] - 2.0f * acc[mb][nb][r];
          rm[mb][r] = fminf(rm[mb][r], dd);
          colm[nb] = fminf(colm[nb], dd);
        }
    #pragma unroll
    for (int nb = 0; nb < 8; ++nb){
      float cm = colm[nb];
      cm = fminf(cm, __shfl_xor(cm, 16, 64));
      cm = fminf(cm, __shfl_xor(cm, 32, 64));
      if (quad == 0)
        atomicMax(&g_ck[bf*NN + j0 + nb*16 + c16], ~fkey(cm));
    }
  }
  #pragma unroll
  for (int mb = 0; mb < 2; ++mb)
    #pragma unroll
    for (int r = 0; r < 4; ++r){
      float v = rm[mb][r];
      v = fminf(v, __shfl_xor(v, 1, 64));
      v = fminf(v, __shfl_xor(v, 2, 64));
      v = fminf(v, __shfl_xor(v, 4, 64));
      v = fminf(v, __shfl_xor(v, 8, 64));
      if (c16 == 0)
        atomicMax(&g_rk[bf*NN + i0 + wrow + mb*16 + quad*4 + r], ~fkey(v));
    }
}

// K3 (new, replaces k_weight + k_coef): one block per batch b — all 5
// frames local, so weights + coefs need no cross-block sync. Also resets
// the atomic key arrays to 0 (their identity) for the next call; each
// entry is reset by the same thread that read it (program-order safe).
__global__ void __launch_bounds__(256) k_fin(){
  const int b = blockIdx.x;                   // 0..3
  const int t = threadIdx.x;
  __shared__ float sw[2][4];
  float swx = 0.f, swy = 0.f;
  #pragma unroll
  for (int f = 0; f < NF; ++f){
    const int bf = b*NF + f;
    #pragma unroll
    for (int i = 0; i < NN/256; ++i){
      int idx = bf*NN + i*256 + t;
      swx += fdec(~g_rk[idx]);
      swy += fdec(~g_ck[idx]);
      g_rk[idx] = 0u; g_ck[idx] = 0u;
    }
  }
  #pragma unroll
  for (int m = 1; m < 64; m <<= 1){
    swx += __shfl_xor(swx, m, 64);
    swy += __shfl_xor(swy, m, 64);
  }
  int w = t >> 6, l = t & 63;
  if (l == 0){ sw[0][w] = swx; sw[1][w] = swy; }
  __syncthreads();
  float SX = sw[0][0] + sw[0][1] + sw[0][2] + sw[0][3];
  float SY = sw[1][0] + sw[1][1] + sw[1][2] + sw[1][3];
  float wx = 1.0f / (1.0f + SX * (1.0f/(NF*NN)));
  float wy = 1.0f / (1.0f + SY * (1.0f/(NF*NN)));
  #pragma unroll
  for (int f = 0; f < NF; ++f){
    const int idx = (b*NF + f)*NDM + t;       // t = d (NDM == 256)
    float mnx = fdec(~g_mnk[0][idx]), mxx = fdec(g_mxk[0][idx]);
    float mny = fdec(~g_mnk[1][idx]), mxy = fdec(g_mxk[1][idx]);
    float sx = wx / (mxx - mnx), sy = wy / (mxy - mny);
    g_coef[idx] = make_float4(sx, -sx * mnx, sy, -sy * mny);
    g_mnk[0][idx] = 0u; g_mxk[0][idx] = 0u;
    g_mnk[1][idx] = 0u; g_mxk[1][idx] = 0u;
  }
}

// K4: out = sx*xb + ox + sy*yb + oy from the L3-hot bf16 copies (halves
// read bytes vs fp32 x,y). One thread per 8 elements; flat 5120-block grid.
__global__ void __launch_bounds__(256) k_out(floatx4* __restrict__ out){
  size_t e0 = ((size_t)blockIdx.x * 256 + threadIdx.x) * 8;  // elem index
  int bf = (int)(e0 >> 19);                   // NN*NDM = 2^19
  int d0 = (int)(e0 & 255);
  short8 xv = *(const short8*)&g_xb[e0];
  short8 yv = *(const short8*)&g_yb[e0];
  const float4* cf = &g_coef[bf*256 + d0];
  floatx4 o0, o1;
  #pragma unroll
  for (int j = 0; j < 4; ++j){
    float4 c = cf[j];
    o0[j] = c.x * bf2f(xv[j]) + c.y + c.z * bf2f(yv[j]) + c.w;
  }
  #pragma unroll
  for (int j = 0; j < 4; ++j){
    float4 c = cf[4 + j];
    o1[j] = c.x * bf2f(xv[4 + j]) + c.y + c.z * bf2f(yv[4 + j]) + c.w;
  }
  __builtin_nontemporal_store(o0, &out[e0 >> 2]);
  __builtin_nontemporal_store(o1, &out[(e0 >> 2) + 1]);
}

extern "C" void kernel_launch(void* const* d_in, const int* in_sizes, int n_in,
                              void* d_out, int out_size, void* d_ws, size_t ws_size,
                              hipStream_t stream) {
  const float* x = (const float*)d_in[0];
  const float* y = (const float*)d_in[1];
  (void)d_ws; (void)ws_size; (void)in_sizes; (void)n_in; (void)out_size;

  k_prep<<<dim3(1280), dim3(256), 0, stream>>>(x, y);
  k_gemm<<<dim3(1280), dim3(256), 0, stream>>>();
  k_fin <<<dim3(4),    dim3(256), 0, stream>>>();
  k_out <<<dim3(5120), dim3(256), 0, stream>>>((floatx4*)d_out);
}

// Round 8
// 214.237 us; speedup vs baseline: 1.6437x; 1.0914x over previous
//
#include <hip/hip_runtime.h>

typedef unsigned int u32;
typedef unsigned short u16;
typedef __attribute__((ext_vector_type(8))) short short8;
typedef __attribute__((ext_vector_type(4))) float floatx4;

#define NB 4
#define NF 5
#define NN 2048
#define NDM 256
#define NBF (NB*NF)          // 20
#define NBFN (NBF*NN)        // 40960
#define NBFD (NBF*NDM)       // 5120

#define AS1 __attribute__((address_space(1)))
#define AS3 __attribute__((address_space(3)))

// Static device scratch; everything read is fully rewritten each call.
__device__ u16    g_xb[(size_t)NBF*NN*NDM];   // bf16 copy of x
__device__ u16    g_yb[(size_t)NBF*NN*NDM];   // bf16 copy of y
__device__ float  g_a2[NBFN];                 // row sumsq of x
__device__ float  g_b2[NBFN];                 // row sumsq of y
__device__ float  g_rpart[(size_t)4*NBFN];    // partial row mins: plane = jq
__device__ float  g_cpart[(size_t)64*NBFN];   // partial col mins: plane = i0t*4+w
__device__ float  g_pmn[2][(size_t)32*NBFD];  // per-chunk partial min over n
__device__ float  g_pmx[2][(size_t)32*NBFD];  // per-chunk partial max over n
__device__ float  g_bfsum[2*NBF];             // per-(dir,bf) sum of mins (atomicAdd)
__device__ float4 g_coef[NBFD];               // sx, ox, sy, oy per (bf,d)

__device__ __forceinline__ u16 cvt_bf16(float f){    // RNE
  u32 b = __float_as_uint(f);
  return (u16)((b + 0x7FFFu + ((b >> 16) & 1u)) >> 16);
}
__device__ __forceinline__ float bf2f(short v){
  return __uint_as_float(((u32)(u16)v) << 16);
}
__device__ __forceinline__ void load16(const void* g, void* l){
  __builtin_amdgcn_global_load_lds((AS1 const void*)g, (AS3 void*)l, 16, 0, 0);
}

// K1: single pass over x,y: bf16 convert + per-(bf,d) partial min/max +
// row sumsq. R8 restructure (R7 lesson: atomic epilogues regress; revert
// elsewhere): thread owns 8 contiguous cols of one row -> two float4
// reads (32B/lane) and ONE short8 store (16B/lane, the G13 sweet spot;
// was 8B ushort4). Row-sumsq via 33-padded LDS matrix reduce; min/max
// via shfl_xor(32) + 9-padded LDS fold (2 lanes/bank = free, m136).
// bf16 values identical (same RNE) -> gemm inputs bit-identical.
__global__ void __launch_bounds__(256) k_prep(const float* __restrict__ x,
                                              const float* __restrict__ y){
  __shared__ float sp2[64][33];               // per-(row, colgrp) sumsq partials
  __shared__ float sp[4][64];                 // stage-2 partials
  __shared__ float smn2[4][32][9], smx2[4][32][9];
  int bi = blockIdx.x;                        // 2 * 20 * 32 = 1280
  if (bi == 0 && threadIdx.x < 2*NBF) g_bfsum[threadIdx.x] = 0.f;
  int tensor = bi >= (NBF*32); int rem = bi - tensor*(NBF*32);
  int bf = rem >> 5; int chunk = rem & 31;
  size_t rbase = (size_t)bf*NN + (size_t)chunk*64;
  const float* src = (tensor ? y : x) + rbase*NDM;
  u16*  dst  = (tensor ? g_yb : g_xb) + rbase*NDM;
  float* sums = (tensor ? g_b2 : g_a2) + bf*NN + chunk*64;
  const int t = threadIdx.x;
  const int g = t >> 5, c = t & 31;           // row-group 0..7, col-group 0..31

  float mn8[8], mx8[8];
  #pragma unroll
  for (int j = 0; j < 8; ++j){ mn8[j] = INFINITY; mx8[j] = -INFINITY; }

  #pragma unroll
  for (int i = 0; i < 8; ++i){
    const int r = g + 8*i;                    // 0..63
    const float4* s4 = (const float4*)(src + (size_t)r*NDM);
    float4 va = s4[2*c], vb = s4[2*c + 1];    // cols 8c..8c+7
    float vv0 = va.x, vv1 = va.y, vv2 = va.z, vv3 = va.w;
    float vv4 = vb.x, vv5 = vb.y, vv6 = vb.z, vv7 = vb.w;
    short8 o;
    o[0] = (short)cvt_bf16(vv0); o[1] = (short)cvt_bf16(vv1);
    o[2] = (short)cvt_bf16(vv2); o[3] = (short)cvt_bf16(vv3);
    o[4] = (short)cvt_bf16(vv4); o[5] = (short)cvt_bf16(vv5);
    o[6] = (short)cvt_bf16(vv6); o[7] = (short)cvt_bf16(vv7);
    *(short8*)(dst + (size_t)r*NDM + 8*c) = o;           // 16B store
    float p = vv0*vv0 + vv1*vv1 + vv2*vv2 + vv3*vv3
            + vv4*vv4 + vv5*vv5 + vv6*vv6 + vv7*vv7;
    sp2[r][c] = p;
    mn8[0]=fminf(mn8[0],vv0); mx8[0]=fmaxf(mx8[0],vv0);
    mn8[1]=fminf(mn8[1],vv1); mx8[1]=fmaxf(mx8[1],vv1);
    mn8[2]=fminf(mn8[2],vv2); mx8[2]=fmaxf(mx8[2],vv2);
    mn8[3]=fminf(mn8[3],vv3); mx8[3]=fmaxf(mx8[3],vv3);
    mn8[4]=fminf(mn8[4],vv4); mx8[4]=fmaxf(mx8[4],vv4);
    mn8[5]=fminf(mn8[5],vv5); mx8[5]=fmaxf(mx8[5],vv5);
    mn8[6]=fminf(mn8[6],vv6); mx8[6]=fmaxf(mx8[6],vv6);
    mn8[7]=fminf(mn8[7],vv7); mx8[7]=fmaxf(mx8[7],vv7);
  }
  __syncthreads();
  // row-sumsq stage 1: 4 threads per row, 8 col-group partials each.
  {
    int rr = t & 63, q = t >> 6;
    float s = 0.f;
    #pragma unroll
    for (int k = 0; k < 8; ++k) s += sp2[rr][q*8 + k];
    sp[q][rr] = s;
  }
  // min/max: combine row-groups 2w and 2w+1 (lanes l and l^32 share c).
  #pragma unroll
  for (int j = 0; j < 8; ++j){
    mn8[j] = fminf(mn8[j], __shfl_xor(mn8[j], 32, 64));
    mx8[j] = fmaxf(mx8[j], __shfl_xor(mx8[j], 32, 64));
  }
  {
    int w = t >> 6, l = t & 63;
    if (l < 32){
      #pragma unroll
      for (int j = 0; j < 8; ++j){ smn2[w][l][j] = mn8[j]; smx2[w][l][j] = mx8[j]; }
    }
  }
  __syncthreads();
  if (t < 64)
    sums[t] = sp[0][t] + sp[1][t] + sp[2][t] + sp[3][t];
  {
    int c2 = t >> 3, j = t & 7;               // d = t
    float mn = fminf(fminf(smn2[0][c2][j], smn2[1][c2][j]),
                     fminf(smn2[2][c2][j], smn2[3][c2][j]));
    float mx = fmaxf(fmaxf(smx2[0][c2][j], smx2[1][c2][j]),
                     fmaxf(smx2[2][c2][j], smx2[3][c2][j]));
    g_pmn[tensor][(size_t)chunk*NBFD + bf*NDM + t] = mn;
    g_pmx[tensor][(size_t)chunk*NBFD + bf*NDM + t] = mx;
  }
}

// K2: GEMM — byte-identical to R5 (proven 64.4us): BK=128 dbuf, plain
// __syncthreads, XCD panel-major swizzle, plane-write epilogue. R7's
// atomicMax epilogue regressed (16 XCD-local blocks contending on the
// same g_ck cachelines: +24us); planes restored.
__global__ void __launch_bounds__(256, 2) k_gemm(){
  __shared__ u16 Bs[2][128*128];              // 2 x 32 KB: [buf][row*128 + k]
  __shared__ float b2s[512];                  // b2 for the j-quarter
  const int orig = blockIdx.x;                // 0..1279
  const int work = (orig & 7)*160 + (orig >> 3);  // XCD gets contiguous 160
  const int bf  = work >> 6;                  // panel-major: (bf,jq) outer
  const int jq  = (work >> 4) & 3;            // cols jq*512 .. +511
  const int i0t = work & 15;
  const int i0  = i0t * 128;
  const int t = threadIdx.x;
  const int w = t >> 6, l = t & 63;
  const int quad = l >> 4, c16 = l & 15;
  const int wrow = w * 32;                    // wave's 32-row slice
  const u16* xb = g_xb + (size_t)bf * NN * NDM;
  const u16* yb = g_yb + (size_t)bf * NN * NDM;

  const float* b2 = g_b2 + bf*NN;
  ((float2*)b2s)[t] = ((const float2*)(b2 + jq*512))[t];

  short8 af[2][8];
  #pragma unroll
  for (int mb = 0; mb < 2; ++mb){
    const u16* rp = xb + (size_t)(i0 + wrow + mb*16 + c16) * NDM + quad*8;
    #pragma unroll
    for (int ks = 0; ks < 8; ++ks)
      af[mb][ks] = *(const short8*)(rp + ks*32);
  }
  const float* a2 = g_a2 + bf*NN + i0 + wrow;
  float a2r[2][4];
  #pragma unroll
  for (int mb = 0; mb < 2; ++mb)
    #pragma unroll
    for (int r = 0; r < 4; ++r)
      a2r[mb][r] = a2[mb*16 + quad*4 + r];

  float rm[2][4];
  #pragma unroll
  for (int mb = 0; mb < 2; ++mb)
    #pragma unroll
    for (int r = 0; r < 4; ++r) rm[mb][r] = INFINITY;

  auto stage = [&](int jt, int h, int bb){
    const int j0 = jq*512 + jt*128;
    #pragma unroll
    for (int q = 0; q < 8; ++q){
      const int row = q*16 + w*4 + (l >> 4);  // 0..127
      const int c = (l & 15) ^ (row & 15);
      load16(yb + (size_t)(j0 + row)*NDM + h*128 + c*8,
             &Bs[bb][(q*16 + w*4)*128]);
    }
  };

  int buf = 0;
  stage(0, 0, 0);
  for (int jj = 0; jj < 4; ++jj){
    const int j0 = jq*512 + jj*128;
    floatx4 acc[2][8] = {};
    #pragma unroll
    for (int h = 0; h < 2; ++h){
      __syncthreads();                        // drains aged prefetch
      const int nit = jj*2 + h + 1;
      if (nit < 8) stage(nit >> 1, nit & 1, buf ^ 1);
      #pragma unroll
      for (int ksl = 0; ksl < 4; ++ksl){
        const int lc = ((ksl*4 + quad) ^ c16) * 8;   // de-swizzle
        short8 bq[8];
        #pragma unroll
        for (int nb = 0; nb < 8; ++nb)
          bq[nb] = *(const short8*)&Bs[buf][(nb*16 + c16)*128 + lc];
        #pragma unroll
        for (int mb = 0; mb < 2; ++mb)
          #pragma unroll
          for (int nb = 0; nb < 8; ++nb)
            acc[mb][nb] = __builtin_amdgcn_mfma_f32_16x16x32_bf16(af[mb][h*4+ksl], bq[nb], acc[mb][nb], 0, 0, 0);
      }
      buf ^= 1;
    }
    float bcol[8], colm[8];
    #pragma unroll
    for (int nb = 0; nb < 8; ++nb){
      bcol[nb] = b2s[jj*128 + nb*16 + c16];
      colm[nb] = INFINITY;
    }
    #pragma unroll
    for (int mb = 0; mb < 2; ++mb)
      #pragma unroll
      for (int r = 0; r < 4; ++r)
        #pragma unroll
        for (int nb = 0; nb < 8; ++nb){
          float dd = a2r[mb][r] + bcol[nb] - 2.0f * acc[mb][nb][r];
          rm[mb][r] = fminf(rm[mb][r], dd);
          colm[nb] = fminf(colm[nb], dd);
        }
    #pragma unroll
    for (int nb = 0; nb < 8; ++nb){
      float cm = colm[nb];
      cm = fminf(cm, __shfl_xor(cm, 16, 64));
      cm = fminf(cm, __shfl_xor(cm, 32, 64));
      if (quad == 0)
        g_cpart[(size_t)(i0t*4 + w)*NBFN + bf*NN + j0 + nb*16 + c16] = cm;
    }
  }
  #pragma unroll
  for (int mb = 0; mb < 2; ++mb)
    #pragma unroll
    for (int r = 0; r < 4; ++r){
      float v = rm[mb][r];
      v = fminf(v, __shfl_xor(v, 1, 64));
      v = fminf(v, __shfl_xor(v, 2, 64));
      v = fminf(v, __shfl_xor(v, 4, 64));
      v = fminf(v, __shfl_xor(v, 8, 64));
      if (c16 == 0)
        g_rpart[(size_t)jq*NBFN + bf*NN + i0 + wrow + mb*16 + quad*4 + r] = v;
    }
}

// K3: hierarchical reduce of partial-min planes -> per-bf sums (atomicAdd).
__global__ void __launch_bounds__(256) k_weight(){
  int bf = blockIdx.x >> 3;
  int chunk = blockIdx.x & 7;
  int i = chunk*256 + threadIdx.x;            // row index in [0,2048)
  size_t base = (size_t)bf*NN + i;
  float m = INFINITY, c = INFINITY;
  #pragma unroll
  for (int p = 0; p < 4; ++p)  m = fminf(m, g_rpart[(size_t)p*NBFN + base]);
  #pragma unroll
  for (int p = 0; p < 64; ++p) c = fminf(c, g_cpart[(size_t)p*NBFN + base]);
  float srow = m, scol = c;
  #pragma unroll
  for (int mm = 1; mm < 64; mm <<= 1){
    srow += __shfl_xor(srow, mm, 64);
    scol += __shfl_xor(scol, mm, 64);
  }
  __shared__ float pr[4], pcn[4];
  int w = threadIdx.x >> 6, l = threadIdx.x & 63;
  if (l == 0){ pr[w] = srow; pcn[w] = scol; }
  __syncthreads();
  if (threadIdx.x == 0){
    atomicAdd(&g_bfsum[bf],       pr[0]+pr[1]+pr[2]+pr[3]);
    atomicAdd(&g_bfsum[NBF + bf], pcn[0]+pcn[1]+pcn[2]+pcn[3]);
  }
}

// K4: fold weights + min/max partials into per-(bf,d) affine coefficients.
__global__ void k_coef(){
  int idx = blockIdx.x * 256 + threadIdx.x;   // < NBFD
  int bf = idx >> 8;
  int b = bf / NF;
  float swx = 0.f, swy = 0.f;
  #pragma unroll
  for (int f = 0; f < NF; ++f){
    swx += g_bfsum[b*NF + f];
    swy += g_bfsum[NBF + b*NF + f];
  }
  float wx = 1.0f / (1.0f + swx * (1.0f/(NF*NN)));
  float wy = 1.0f / (1.0f + swy * (1.0f/(NF*NN)));
  float mnx = INFINITY, mxx = -INFINITY, mny = INFINITY, mxy = -INFINITY;
  #pragma unroll
  for (int c = 0; c < 32; ++c){
    mnx = fminf(mnx, g_pmn[0][(size_t)c*NBFD + idx]);
    mxx = fmaxf(mxx, g_pmx[0][(size_t)c*NBFD + idx]);
    mny = fminf(mny, g_pmn[1][(size_t)c*NBFD + idx]);
    mxy = fmaxf(mxy, g_pmx[1][(size_t)c*NBFD + idx]);
  }
  float sx = wx / (mxx - mnx), sy = wy / (mxy - mny);
  g_coef[idx] = make_float4(sx, -sx * mnx, sy, -sy * mny);
}

// K5: out = sx*xb + ox + sy*yb + oy from the L3-hot bf16 copies (halves
// read bytes vs fp32 x,y). One thread per 8 elements; flat 5120-block grid.
__global__ void __launch_bounds__(256) k_out(floatx4* __restrict__ out){
  size_t e0 = ((size_t)blockIdx.x * 256 + threadIdx.x) * 8;  // elem index
  int bf = (int)(e0 >> 19);                   // NN*NDM = 2^19
  int d0 = (int)(e0 & 255);
  short8 xv = *(const short8*)&g_xb[e0];
  short8 yv = *(const short8*)&g_yb[e0];
  const float4* cf = &g_coef[bf*256 + d0];
  floatx4 o0, o1;
  #pragma unroll
  for (int j = 0; j < 4; ++j){
    float4 c = cf[j];
    o0[j] = c.x * bf2f(xv[j]) + c.y + c.z * bf2f(yv[j]) + c.w;
  }
  #pragma unroll
  for (int j = 0; j < 4; ++j){
    float4 c = cf[4 + j];
    o1[j] = c.x * bf2f(xv[4 + j]) + c.y + c.z * bf2f(yv[4 + j]) + c.w;
  }
  __builtin_nontemporal_store(o0, &out[e0 >> 2]);
  __builtin_nontemporal_store(o1, &out[(e0 >> 2) + 1]);
}

extern "C" void kernel_launch(void* const* d_in, const int* in_sizes, int n_in,
                              void* d_out, int out_size, void* d_ws, size_t ws_size,
                              hipStream_t stream) {
  const float* x = (const float*)d_in[0];
  const float* y = (const float*)d_in[1];
  (void)d_ws; (void)ws_size; (void)in_sizes; (void)n_in; (void)out_size;

  k_prep  <<<dim3(1280), dim3(256), 0, stream>>>(x, y);
  k_gemm  <<<dim3(1280), dim3(256), 0, stream>>>();
  k_weight<<<dim3(160),  dim3(256), 0, stream>>>();
  k_coef  <<<dim3(20),   dim3(256), 0, stream>>>();
  k_out   <<<dim3(5120), dim3(256), 0, stream>>>((floatx4*)d_out);
}

// Round 9
// 208.724 us; speedup vs baseline: 1.6871x; 1.0264x over previous
//
#include <hip/hip_runtime.h>

typedef unsigned int u32;
typedef unsigned short u16;
typedef __attribute__((ext_vector_type(8))) short short8;
typedef __attribute__((ext_vector_type(4))) float floatx4;

#define NB 4
#define NF 5
#define NN 2048
#define NDM 256
#define NBF (NB*NF)          // 20
#define NBFN (NBF*NN)        // 40960
#define NBFD (NBF*NDM)       // 5120

#define AS1 __attribute__((address_space(1)))
#define AS3 __attribute__((address_space(3)))

// Static device scratch; everything read is fully rewritten each call.
__device__ u16    g_xb[(size_t)NBF*NN*NDM];   // bf16 copy of x
__device__ u16    g_yb[(size_t)NBF*NN*NDM];   // bf16 copy of y
__device__ float  g_a2[NBFN];                 // row sumsq of x
__device__ float  g_b2[NBFN];                 // row sumsq of y
__device__ float  g_rpart[(size_t)4*NBFN];    // partial row mins: plane = jq
__device__ float  g_cpart[(size_t)64*NBFN];   // partial col mins: plane = i0t*4+w
__device__ float  g_pmn[2][(size_t)32*NBFD];  // per-chunk partial min over n
__device__ float  g_pmx[2][(size_t)32*NBFD];  // per-chunk partial max over n
__device__ float  g_bfsum[2*NBF];             // per-(dir,bf) sum of mins (atomicAdd)
__device__ float4 g_coef[NBFD];               // sx, ox, sy, oy per (bf,d)

__device__ __forceinline__ u16 cvt_bf16(float f){    // RNE
  u32 b = __float_as_uint(f);
  return (u16)((b + 0x7FFFu + ((b >> 16) & 1u)) >> 16);
}
__device__ __forceinline__ float bf2f(short v){
  return __uint_as_float(((u32)(u16)v) << 16);
}
__device__ __forceinline__ void load16(const void* g, void* l){
  __builtin_amdgcn_global_load_lds((AS1 const void*)g, (AS3 void*)l, 16, 0, 0);
}

// K1: single pass over x,y (byte-identical to R8): bf16 convert +
// per-(bf,d) partial min/max + row sumsq. Thread owns 8 contiguous cols
// of one row -> two float4 reads (32B/lane), one short8 store (16B/lane).
__global__ void __launch_bounds__(256) k_prep(const float* __restrict__ x,
                                              const float* __restrict__ y){
  __shared__ float sp2[64][33];               // per-(row, colgrp) sumsq partials
  __shared__ float sp[4][64];                 // stage-2 partials
  __shared__ float smn2[4][32][9], smx2[4][32][9];
  int bi = blockIdx.x;                        // 2 * 20 * 32 = 1280
  if (bi == 0 && threadIdx.x < 2*NBF) g_bfsum[threadIdx.x] = 0.f;
  int tensor = bi >= (NBF*32); int rem = bi - tensor*(NBF*32);
  int bf = rem >> 5; int chunk = rem & 31;
  size_t rbase = (size_t)bf*NN + (size_t)chunk*64;
  const float* src = (tensor ? y : x) + rbase*NDM;
  u16*  dst  = (tensor ? g_yb : g_xb) + rbase*NDM;
  float* sums = (tensor ? g_b2 : g_a2) + bf*NN + chunk*64;
  const int t = threadIdx.x;
  const int g = t >> 5, c = t & 31;           // row-group 0..7, col-group 0..31

  float mn8[8], mx8[8];
  #pragma unroll
  for (int j = 0; j < 8; ++j){ mn8[j] = INFINITY; mx8[j] = -INFINITY; }

  #pragma unroll
  for (int i = 0; i < 8; ++i){
    const int r = g + 8*i;                    // 0..63
    const float4* s4 = (const float4*)(src + (size_t)r*NDM);
    float4 va = s4[2*c], vb = s4[2*c + 1];    // cols 8c..8c+7
    float vv0 = va.x, vv1 = va.y, vv2 = va.z, vv3 = va.w;
    float vv4 = vb.x, vv5 = vb.y, vv6 = vb.z, vv7 = vb.w;
    short8 o;
    o[0] = (short)cvt_bf16(vv0); o[1] = (short)cvt_bf16(vv1);
    o[2] = (short)cvt_bf16(vv2); o[3] = (short)cvt_bf16(vv3);
    o[4] = (short)cvt_bf16(vv4); o[5] = (short)cvt_bf16(vv5);
    o[6] = (short)cvt_bf16(vv6); o[7] = (short)cvt_bf16(vv7);
    *(short8*)(dst + (size_t)r*NDM + 8*c) = o;           // 16B store
    float p = vv0*vv0 + vv1*vv1 + vv2*vv2 + vv3*vv3
            + vv4*vv4 + vv5*vv5 + vv6*vv6 + vv7*vv7;
    sp2[r][c] = p;
    mn8[0]=fminf(mn8[0],vv0); mx8[0]=fmaxf(mx8[0],vv0);
    mn8[1]=fminf(mn8[1],vv1); mx8[1]=fmaxf(mx8[1],vv1);
    mn8[2]=fminf(mn8[2],vv2); mx8[2]=fmaxf(mx8[2],vv2);
    mn8[3]=fminf(mn8[3],vv3); mx8[3]=fmaxf(mx8[3],vv3);
    mn8[4]=fminf(mn8[4],vv4); mx8[4]=fmaxf(mx8[4],vv4);
    mn8[5]=fminf(mn8[5],vv5); mx8[5]=fmaxf(mx8[5],vv5);
    mn8[6]=fminf(mn8[6],vv6); mx8[6]=fmaxf(mx8[6],vv6);
    mn8[7]=fminf(mn8[7],vv7); mx8[7]=fmaxf(mx8[7],vv7);
  }
  __syncthreads();
  // row-sumsq stage 1: 4 threads per row, 8 col-group partials each.
  {
    int rr = t & 63, q = t >> 6;
    float s = 0.f;
    #pragma unroll
    for (int k = 0; k < 8; ++k) s += sp2[rr][q*8 + k];
    sp[q][rr] = s;
  }
  // min/max: combine row-groups 2w and 2w+1 (lanes l and l^32 share c).
  #pragma unroll
  for (int j = 0; j < 8; ++j){
    mn8[j] = fminf(mn8[j], __shfl_xor(mn8[j], 32, 64));
    mx8[j] = fmaxf(mx8[j], __shfl_xor(mx8[j], 32, 64));
  }
  {
    int w = t >> 6, l = t & 63;
    if (l < 32){
      #pragma unroll
      for (int j = 0; j < 8; ++j){ smn2[w][l][j] = mn8[j]; smx2[w][l][j] = mx8[j]; }
    }
  }
  __syncthreads();
  if (t < 64)
    sums[t] = sp[0][t] + sp[1][t] + sp[2][t] + sp[3][t];
  {
    int c2 = t >> 3, j = t & 7;               // d = t
    float mn = fminf(fminf(smn2[0][c2][j], smn2[1][c2][j]),
                     fminf(smn2[2][c2][j], smn2[3][c2][j]));
    float mx = fmaxf(fmaxf(smx2[0][c2][j], smx2[1][c2][j]),
                     fmaxf(smx2[2][c2][j], smx2[3][c2][j]));
    g_pmn[tensor][(size_t)chunk*NBFD + bf*NDM + t] = mn;
    g_pmx[tensor][(size_t)chunk*NBFD + bf*NDM + t] = mx;
  }
}

// K2: GEMM — byte-identical to R5/R8 (proven 64.4-65.2us): BK=128 dbuf,
// plain __syncthreads, XCD panel-major swizzle, plane-write epilogue.
__global__ void __launch_bounds__(256, 2) k_gemm(){
  __shared__ u16 Bs[2][128*128];              // 2 x 32 KB: [buf][row*128 + k]
  __shared__ float b2s[512];                  // b2 for the j-quarter
  const int orig = blockIdx.x;                // 0..1279
  const int work = (orig & 7)*160 + (orig >> 3);  // XCD gets contiguous 160
  const int bf  = work >> 6;                  // panel-major: (bf,jq) outer
  const int jq  = (work >> 4) & 3;            // cols jq*512 .. +511
  const int i0t = work & 15;
  const int i0  = i0t * 128;
  const int t = threadIdx.x;
  const int w = t >> 6, l = t & 63;
  const int quad = l >> 4, c16 = l & 15;
  const int wrow = w * 32;                    // wave's 32-row slice
  const u16* xb = g_xb + (size_t)bf * NN * NDM;
  const u16* yb = g_yb + (size_t)bf * NN * NDM;

  const float* b2 = g_b2 + bf*NN;
  ((float2*)b2s)[t] = ((const float2*)(b2 + jq*512))[t];

  short8 af[2][8];
  #pragma unroll
  for (int mb = 0; mb < 2; ++mb){
    const u16* rp = xb + (size_t)(i0 + wrow + mb*16 + c16) * NDM + quad*8;
    #pragma unroll
    for (int ks = 0; ks < 8; ++ks)
      af[mb][ks] = *(const short8*)(rp + ks*32);
  }
  const float* a2 = g_a2 + bf*NN + i0 + wrow;
  float a2r[2][4];
  #pragma unroll
  for (int mb = 0; mb < 2; ++mb)
    #pragma unroll
    for (int r = 0; r < 4; ++r)
      a2r[mb][r] = a2[mb*16 + quad*4 + r];

  float rm[2][4];
  #pragma unroll
  for (int mb = 0; mb < 2; ++mb)
    #pragma unroll
    for (int r = 0; r < 4; ++r) rm[mb][r] = INFINITY;

  auto stage = [&](int jt, int h, int bb){
    const int j0 = jq*512 + jt*128;
    #pragma unroll
    for (int q = 0; q < 8; ++q){
      const int row = q*16 + w*4 + (l >> 4);  // 0..127
      const int c = (l & 15) ^ (row & 15);
      load16(yb + (size_t)(j0 + row)*NDM + h*128 + c*8,
             &Bs[bb][(q*16 + w*4)*128]);
    }
  };

  int buf = 0;
  stage(0, 0, 0);
  for (int jj = 0; jj < 4; ++jj){
    const int j0 = jq*512 + jj*128;
    floatx4 acc[2][8] = {};
    #pragma unroll
    for (int h = 0; h < 2; ++h){
      __syncthreads();                        // drains aged prefetch
      const int nit = jj*2 + h + 1;
      if (nit < 8) stage(nit >> 1, nit & 1, buf ^ 1);
      #pragma unroll
      for (int ksl = 0; ksl < 4; ++ksl){
        const int lc = ((ksl*4 + quad) ^ c16) * 8;   // de-swizzle
        short8 bq[8];
        #pragma unroll
        for (int nb = 0; nb < 8; ++nb)
          bq[nb] = *(const short8*)&Bs[buf][(nb*16 + c16)*128 + lc];
        #pragma unroll
        for (int mb = 0; mb < 2; ++mb)
          #pragma unroll
          for (int nb = 0; nb < 8; ++nb)
            acc[mb][nb] = __builtin_amdgcn_mfma_f32_16x16x32_bf16(af[mb][h*4+ksl], bq[nb], acc[mb][nb], 0, 0, 0);
      }
      buf ^= 1;
    }
    float bcol[8], colm[8];
    #pragma unroll
    for (int nb = 0; nb < 8; ++nb){
      bcol[nb] = b2s[jj*128 + nb*16 + c16];
      colm[nb] = INFINITY;
    }
    #pragma unroll
    for (int mb = 0; mb < 2; ++mb)
      #pragma unroll
      for (int r = 0; r < 4; ++r)
        #pragma unroll
        for (int nb = 0; nb < 8; ++nb){
          float dd = a2r[mb][r] + bcol[nb] - 2.0f * acc[mb][nb][r];
          rm[mb][r] = fminf(rm[mb][r], dd);
          colm[nb] = fminf(colm[nb], dd);
        }
    #pragma unroll
    for (int nb = 0; nb < 8; ++nb){
      float cm = colm[nb];
      cm = fminf(cm, __shfl_xor(cm, 16, 64));
      cm = fminf(cm, __shfl_xor(cm, 32, 64));
      if (quad == 0)
        g_cpart[(size_t)(i0t*4 + w)*NBFN + bf*NN + j0 + nb*16 + c16] = cm;
    }
  }
  #pragma unroll
  for (int mb = 0; mb < 2; ++mb)
    #pragma unroll
    for (int r = 0; r < 4; ++r){
      float v = rm[mb][r];
      v = fminf(v, __shfl_xor(v, 1, 64));
      v = fminf(v, __shfl_xor(v, 2, 64));
      v = fminf(v, __shfl_xor(v, 4, 64));
      v = fminf(v, __shfl_xor(v, 8, 64));
      if (c16 == 0)
        g_rpart[(size_t)jq*NBFN + bf*NN + i0 + wrow + mb*16 + quad*4 + r] = v;
    }
}

// K3: hierarchical reduce of partial-min planes -> per-bf sums (atomicAdd).
__global__ void __launch_bounds__(256) k_weight(){
  int bf = blockIdx.x >> 3;
  int chunk = blockIdx.x & 7;
  int i = chunk*256 + threadIdx.x;            // row index in [0,2048)
  size_t base = (size_t)bf*NN + i;
  float m = INFINITY, c = INFINITY;
  #pragma unroll
  for (int p = 0; p < 4; ++p)  m = fminf(m, g_rpart[(size_t)p*NBFN + base]);
  #pragma unroll
  for (int p = 0; p < 64; ++p) c = fminf(c, g_cpart[(size_t)p*NBFN + base]);
  float srow = m, scol = c;
  #pragma unroll
  for (int mm = 1; mm < 64; mm <<= 1){
    srow += __shfl_xor(srow, mm, 64);
    scol += __shfl_xor(scol, mm, 64);
  }
  __shared__ float pr[4], pcn[4];
  int w = threadIdx.x >> 6, l = threadIdx.x & 63;
  if (l == 0){ pr[w] = srow; pcn[w] = scol; }
  __syncthreads();
  if (threadIdx.x == 0){
    atomicAdd(&g_bfsum[bf],       pr[0]+pr[1]+pr[2]+pr[3]);
    atomicAdd(&g_bfsum[NBF + bf], pcn[0]+pcn[1]+pcn[2]+pcn[3]);
  }
}

// K4: fold weights + min/max partials into per-(bf,d) affine coefficients.
__global__ void k_coef(){
  int idx = blockIdx.x * 256 + threadIdx.x;   // < NBFD
  int bf = idx >> 8;
  int b = bf / NF;
  float swx = 0.f, swy = 0.f;
  #pragma unroll
  for (int f = 0; f < NF; ++f){
    swx += g_bfsum[b*NF + f];
    swy += g_bfsum[NBF + b*NF + f];
  }
  float wx = 1.0f / (1.0f + swx * (1.0f/(NF*NN)));
  float wy = 1.0f / (1.0f + swy * (1.0f/(NF*NN)));
  float mnx = INFINITY, mxx = -INFINITY, mny = INFINITY, mxy = -INFINITY;
  #pragma unroll
  for (int c = 0; c < 32; ++c){
    mnx = fminf(mnx, g_pmn[0][(size_t)c*NBFD + idx]);
    mxx = fmaxf(mxx, g_pmx[0][(size_t)c*NBFD + idx]);
    mny = fminf(mny, g_pmn[1][(size_t)c*NBFD + idx]);
    mxy = fmaxf(mxy, g_pmx[1][(size_t)c*NBFD + idx]);
  }
  float sx = wx / (mxx - mnx), sy = wy / (mxy - mny);
  g_coef[idx] = make_float4(sx, -sx * mnx, sy, -sy * mny);
}

// K5: out = sx*xb + ox + sy*yb + oy. R9 restructure: block = (bf, 64-row
// chunk); thread owns a FIXED 8-col group and loads its 8 coef float4s
// ONCE into registers (was: re-fetched per row by every thread -> 128B
// of coef VMEM per 32B payload), then streams 8 rows of 16B-coalesced
// loads/NT-stores. Coef VMEM per thread: 8 per 64 rows (was 8 per row).
__global__ void __launch_bounds__(256) k_out(floatx4* __restrict__ out){
  const int bk = blockIdx.x;                  // 0..639 = bf*32 + chunk
  const int bf = bk >> 5;
  const int r0 = (bk & 31) * 64;              // 64-row chunk
  const int t = threadIdx.x;
  const int c = t & 31;                       // col-group: cols 8c..8c+7
  const int rl = t >> 5;                      // row lane 0..7
  const float4* cf = &g_coef[bf*256 + 8*c];
  float4 c0 = cf[0], c1 = cf[1], c2 = cf[2], c3 = cf[3];
  float4 c4 = cf[4], c5 = cf[5], c6 = cf[6], c7 = cf[7];
  size_t base = ((size_t)bf*NN + r0 + rl)*NDM + 8*c;
  #pragma unroll
  for (int i = 0; i < 8; ++i){
    size_t e0 = base + (size_t)i*8*NDM;       // 8 rows apart
    short8 xv = *(const short8*)&g_xb[e0];
    short8 yv = *(const short8*)&g_yb[e0];
    floatx4 o0, o1;
    o0[0] = c0.x*bf2f(xv[0]) + c0.y + c0.z*bf2f(yv[0]) + c0.w;
    o0[1] = c1.x*bf2f(xv[1]) + c1.y + c1.z*bf2f(yv[1]) + c1.w;
    o0[2] = c2.x*bf2f(xv[2]) + c2.y + c2.z*bf2f(yv[2]) + c2.w;
    o0[3] = c3.x*bf2f(xv[3]) + c3.y + c3.z*bf2f(yv[3]) + c3.w;
    o1[0] = c4.x*bf2f(xv[4]) + c4.y + c4.z*bf2f(yv[4]) + c4.w;
    o1[1] = c5.x*bf2f(xv[5]) + c5.y + c5.z*bf2f(yv[5]) + c5.w;
    o1[2] = c6.x*bf2f(xv[6]) + c6.y + c6.z*bf2f(yv[6]) + c6.w;
    o1[3] = c7.x*bf2f(xv[7]) + c7.y + c7.z*bf2f(yv[7]) + c7.w;
    __builtin_nontemporal_store(o0, &out[e0 >> 2]);
    __builtin_nontemporal_store(o1, &out[(e0 >> 2) + 1]);
  }
}

extern "C" void kernel_launch(void* const* d_in, const int* in_sizes, int n_in,
                              void* d_out, int out_size, void* d_ws, size_t ws_size,
                              hipStream_t stream) {
  const float* x = (const float*)d_in[0];
  const float* y = (const float*)d_in[1];
  (void)d_ws; (void)ws_size; (void)in_sizes; (void)n_in; (void)out_size;

  k_prep  <<<dim3(1280), dim3(256), 0, stream>>>(x, y);
  k_gemm  <<<dim3(1280), dim3(256), 0, stream>>>();
  k_weight<<<dim3(160),  dim3(256), 0, stream>>>();
  k_coef  <<<dim3(20),   dim3(256), 0, stream>>>();
  k_out   <<<dim3(640),  dim3(256), 0, stream>>>((floatx4*)d_out);
}